// Round 4
// baseline (1037.382 us; speedup 1.0000x reference)
//
#include <hip/hip_runtime.h>
#include <stdint.h>

// LNSLinear inference: out[m,n] = sign(S[m,n]) * P[m,n] + bias[n]
//   P = |x| @ |w|^T (bf16), S = sign(x) @ sign(w)^T (exact, +-1 bf16)
// M = 262144, N = 256, K = 256.
// v5: LDS stores ONE signed-bf16 plane (abs/sgn derived in regs after ds_read:
//     v_and / v_and_or_b32).  sA 8 KB + sB 16 KB = 24.5 KB -> LDS allows 6
//     blocks/CU; launch_bounds(256,5) -> 5 blocks/CU (~62% occ, 2x v4).
//     Rows are 64 B; bank conflicts fixed by XOR swizzle slot^=(row&3):
//     A swizzled on ds_write+ds_read, B pre-swizzled global source with linear
//     global_load_lds dest + swizzled ds_read (both-sides involution).
//     Waits per iter: vmcnt(2) [A regs; B-DMA in flight] + vmcnt(2) [B-DMA
//     done; next A regs in flight] + 1 barrier.  No vmcnt(0) steady-state.

#define K_DIM 256
#define N_DIM 256
#define BM 64
#define BN 128
#define BK 32
#define NKBLK 8   // K_DIM / BK

typedef float f32x4 __attribute__((ext_vector_type(4)));
typedef __bf16 bf16x8 __attribute__((ext_vector_type(8)));
typedef unsigned short u16x4v __attribute__((ext_vector_type(4)));
typedef unsigned short u16x8v __attribute__((ext_vector_type(8)));
typedef unsigned int u32x4v __attribute__((ext_vector_type(4)));

// ---------- pre-kernel: W fp32 [N][K] -> Wp signed bf16 [N][K] row-major ----------
__global__ void w_convert_kernel(const float* __restrict__ W, unsigned short* __restrict__ Wp) {
    int t = blockIdx.x * 256 + threadIdx.x;  // 16384 threads x 4 elems
    float4 v = *(const float4*)(W + (size_t)t * 4);
    float vv[4] = {v.x, v.y, v.z, v.w};
    u16x4v o;
#pragma unroll
    for (int j = 0; j < 4; ++j)
        o[j] = __builtin_bit_cast(unsigned short, (__bf16)vv[j]);
    *(u16x4v*)(Wp + (size_t)t * 4) = o;
}

__device__ __forceinline__ void gload_lds16(const void* g, void* l) {
    __builtin_amdgcn_global_load_lds(
        (const __attribute__((address_space(1))) unsigned int*)g,
        (__attribute__((address_space(3))) unsigned int*)l, 16, 0, 0);
}

// Split 8 signed bf16 (as 4 u32) into abs plane and +-1 sign plane.
__device__ __forceinline__ void unpack_abs_sgn(const unsigned short* rp, bf16x8& ab, bf16x8& sg) {
    u32x4v v = *(const u32x4v*)rp;
    u32x4v a, s;
#pragma unroll
    for (int j = 0; j < 4; ++j) {
        a[j] = v[j] & 0x7FFF7FFFu;                      // v_and
        s[j] = (v[j] & 0x80008000u) | 0x3F803F80u;      // v_and_or_b32
    }
    ab = __builtin_bit_cast(bf16x8, a);
    sg = __builtin_bit_cast(bf16x8, s);
}

// ---------- main kernel ----------
__global__ __launch_bounds__(256, 5)
void lns_gemm_kernel(const float* __restrict__ X, const unsigned short* __restrict__ Wp,
                     const float* __restrict__ bias, float* __restrict__ out) {
    // Signed bf16 tiles; row = 32 bf16 = 64 B = 4 chunks of 16 B, XOR-swizzled.
    __shared__ __attribute__((aligned(16))) unsigned short sA[2][BM * 32];   // 8 KB
    __shared__ __attribute__((aligned(16))) unsigned short sB[2][BN * 32];   // 16 KB

    const int tid  = threadIdx.x;
    const int lane = tid & 63;
    const int wave = tid >> 6;
    const int quad = lane >> 4;
    const int l16  = lane & 15;
    const int mb   = blockIdx.y;
    const int nb   = blockIdx.x;
    const int wm   = (wave >> 1) * 32;   // 2 waves down M
    const int wn   = (wave & 1) * 64;    // 2 waves across N

    // ---- A staging: 256 threads x 8 fp32 = 64 rows x 32 k; write swizzled ----
    const int ar = tid >> 2;             // row 0..63
    const int aq = tid & 3;              // k-chunk (8 floats read; 8 bf16 written)
    const float* gA = X + (size_t)(mb * BM + ar) * K_DIM + aq * 8;
    const int aslot = aq ^ (ar & 3);
    unsigned short* const wA0 = &sA[0][ar * 32 + aslot * 8];
    unsigned short* const wA1 = &sA[1][ar * 32 + aslot * 8];

    // ---- B staging: XOR-pre-swizzled global source, linear LDS dest ----
    const unsigned short* gB[2];
    int dstB[2];
#pragma unroll
    for (int i = 0; i < 2; ++i) {
        int f = i * 256 + tid;           // chunk 0..511
        int r = f >> 2;                  // B row 0..127
        int g = (f & 3) ^ (r & 3);       // global k-chunk held in this slot
        gB[i] = Wp + (size_t)(nb * BN + r) * K_DIM + g * 8;
        dstB[i] = (i * 256 + wave * 64) * 8;   // u16 units, wave-uniform base
    }

    f32x4 accP[2][4], accS[2][4];
#pragma unroll
    for (int i = 0; i < 2; ++i)
#pragma unroll
        for (int j = 0; j < 4; ++j) {
            accP[i][j] = (f32x4)(0.0f);
            accS[i][j] = (f32x4)(0.0f);
        }

    f32x4 ra[2];  // pending A tile (8 fp32 per thread)

#define LOAD_A(kbv) do { \
        const f32x4* _p = (const f32x4*)(gA + (kbv) * BK); \
        ra[0] = _p[0]; ra[1] = _p[1]; \
    } while (0)

#define CONV_WRITE_A(dst) do { \
        u16x8v _v; \
        _Pragma("unroll") \
        for (int _j = 0; _j < 4; ++_j) { \
            _v[_j]     = __builtin_bit_cast(unsigned short, (__bf16)ra[0][_j]); \
            _v[_j + 4] = __builtin_bit_cast(unsigned short, (__bf16)ra[1][_j]); \
        } \
        *(u16x8v*)(dst) = _v; \
    } while (0)

    // ---- prologue ----
    LOAD_A(0);                                              // A(0) x2
#pragma unroll
    for (int i = 0; i < 2; ++i) gload_lds16(gB[i], &sB[0][dstB[i]]);        // B(0) x2
    asm volatile("s_waitcnt vmcnt(2)" ::: "memory");        // A(0) regs done; B(0) in flight
    CONV_WRITE_A(wA0);
    LOAD_A(1);                                              // A(1) x2
#pragma unroll
    for (int i = 0; i < 2; ++i) gload_lds16(gB[i] + 32, &sB[1][dstB[i]]);   // B(1) x2
    // B(0) complete (A(1)+B(1)=4 stay in flight); my ds_write visible; sync.
    asm volatile("s_waitcnt vmcnt(4) lgkmcnt(0)\n\ts_barrier" ::: "memory");

    // ---- main loop: entering kb, outstanding = [A(kb+1) x2] (+B(kb+1) x2 after top) ----
#pragma unroll
    for (int kb = 0; kb < NKBLK; ++kb) {
        const int cur = kb & 1;
        const int nxt = cur ^ 1;

        // B(kb+1) DMA at top (target buffer freed by end-of-(kb-1) barrier).
        if (kb >= 1 && kb + 1 < NKBLK) {
#pragma unroll
            for (int i = 0; i < 2; ++i)
                gload_lds16(gB[i] + (kb + 1) * 32, &sB[nxt][dstB[i]]);
        }

        // ---- fragments from LDS (swizzled) + in-reg abs/sgn split + MFMA ----
        bf16x8 aab[2], asg[2];
#pragma unroll
        for (int mi = 0; mi < 2; ++mi) {
            int m = wm + mi * 16 + l16;
            unpack_abs_sgn(&sA[cur][m * 32 + (quad ^ (m & 3)) * 8], aab[mi], asg[mi]);
        }
#pragma unroll
        for (int ni = 0; ni < 4; ++ni) {
            int r = wn + ni * 16 + l16;
            bf16x8 bab, bsg;
            unpack_abs_sgn(&sB[cur][r * 32 + (quad ^ (r & 3)) * 8], bab, bsg);
            accP[0][ni] = __builtin_amdgcn_mfma_f32_16x16x32_bf16(aab[0], bab, accP[0][ni], 0, 0, 0);
            accP[1][ni] = __builtin_amdgcn_mfma_f32_16x16x32_bf16(aab[1], bab, accP[1][ni], 0, 0, 0);
            accS[0][ni] = __builtin_amdgcn_mfma_f32_16x16x32_bf16(asg[0], bsg, accS[0][ni], 0, 0, 0);
            accS[1][ni] = __builtin_amdgcn_mfma_f32_16x16x32_bf16(asg[1], bsg, accS[1][ni], 0, 0, 0);
        }

        if (kb + 1 < NKBLK) {
            // A(kb+1) regs landed (issued last iter; MFMA covered the latency);
            // B(kb+1) DMA (2 ops, younger) stays in flight.
            asm volatile("s_waitcnt vmcnt(2)" ::: "memory");
            CONV_WRITE_A((kb & 1) ? wA0 : wA1);  // -> sA[nxt]
        }
        if (kb + 2 < NKBLK) LOAD_A(kb + 2);
        if (kb + 1 < NKBLK) {
            // B(kb+1) complete (A(kb+2) x2 stays in flight); writes visible; sync.
            if (kb + 2 < NKBLK)
                asm volatile("s_waitcnt vmcnt(2) lgkmcnt(0)\n\ts_barrier" ::: "memory");
            else
                asm volatile("s_waitcnt vmcnt(0) lgkmcnt(0)\n\ts_barrier" ::: "memory");
        }
    }

    // ---- epilogue: C/D layout col = l16, row = quad*4 + reg ----
#pragma unroll
    for (int ni = 0; ni < 4; ++ni) {
        int n   = nb * BN + wn + ni * 16 + l16;
        float b = bias[n];
#pragma unroll
        for (int mi = 0; mi < 2; ++mi) {
            int mbase = mb * BM + wm + mi * 16 + quad * 4;
#pragma unroll
            for (int r = 0; r < 4; ++r) {
                float p = accP[mi][ni][r];
                float s = accS[mi][ni][r];
                float v = (s > 0.0f) ? p : ((s < 0.0f) ? -p : 0.0f);
                out[(size_t)(mbase + r) * N_DIM + n] = v + b;
            }
        }
    }
}

extern "C" void kernel_launch(void* const* d_in, const int* in_sizes, int n_in,
                              void* d_out, int out_size, void* d_ws, size_t ws_size,
                              hipStream_t stream) {
    const float* x    = (const float*)d_in[0];
    const float* w    = (const float*)d_in[1];
    const float* bias = (const float*)d_in[2];
    float* out        = (float*)d_out;
    unsigned short* Wp = (unsigned short*)d_ws;  // 128 KB: signed bf16 [N][K]

    const int M = in_sizes[0] / K_DIM;  // 262144

    w_convert_kernel<<<dim3(64, 1, 1), dim3(256, 1, 1), 0, stream>>>(w, Wp);

    dim3 grid(N_DIM / BN, M / BM, 1);  // (2, 4096): nb fastest -> paired blocks share x slab in L2/L3
    dim3 block(256, 1, 1);
    lns_gemm_kernel<<<grid, block, 0, stream>>>(x, Wp, bias, out);
}

// Round 5
// 705.398 us; speedup vs baseline: 1.4706x; 1.4706x over previous
//
#include <hip/hip_runtime.h>
#include <stdint.h>

// LNSLinear inference: out[m,n] = sign(S[m,n]) * P[m,n] + bias[n]
//   P = |x| @ |w|^T (bf16), S = sign(x) @ sign(w)^T (exact, +-1 bf16)
// M = 262144, N = 256, K = 256.
// v6: barrier-free, LDS-free. Each wave owns a private 32x64 output tile.
//     A fragments loaded DIRECTLY from fp32 X (wave covers 16 rows x 128 B
//     contiguous per frag -> full 64 B sectors), converted abs/sgn in-reg,
//     prefetched 2 K-iters deep (ping-pong reg buffers) to cover HBM latency.
//     B fragments loaded directly from L2-resident Wp (separate abs/sgn bf16
//     planes, 256 KB total), issued before the A-prefetch each iter so
//     in-order vmem completion gives counted B waits with A still in flight.
//     No __syncthreads, no global_load_lds, no LDS: waves are fully
//     independent streams (12+/CU) instead of 2-3 barrier-coupled blocks.
//     v5 lesson: launch_bounds must leave room for acc+working set ->
//     (256,3) caps at ~170 vs ~134 needed. No spill.

#define K_DIM 256
#define N_DIM 256
#define PLANE (N_DIM * K_DIM)  // u16 offset of sign plane in Wp

typedef float f32x4 __attribute__((ext_vector_type(4)));
typedef __bf16 bf16x8 __attribute__((ext_vector_type(8)));
typedef unsigned short u16x4v __attribute__((ext_vector_type(4)));
typedef unsigned short u16x8v __attribute__((ext_vector_type(8)));
typedef unsigned int u32x4v __attribute__((ext_vector_type(4)));

// ---------- pre-kernel: W fp32 [N][K] -> Wp abs-bf16 plane [N*K] + sgn plane [N*K] ----------
__global__ void w_convert_kernel(const float* __restrict__ W, unsigned short* __restrict__ Wp) {
    int t = blockIdx.x * 256 + threadIdx.x;  // 16384 threads x 4 elems
    float4 v = *(const float4*)(W + (size_t)t * 4);
    float vv[4] = {v.x, v.y, v.z, v.w};
    u16x4v a, s;
#pragma unroll
    for (int j = 0; j < 4; ++j) {
        a[j] = __builtin_bit_cast(unsigned short, (__bf16)__builtin_fabsf(vv[j]));
        unsigned int u = __float_as_uint(vv[j]);
        s[j] = (unsigned short)(0x3F80u | ((u >> 16) & 0x8000u));
    }
    *(u16x4v*)(Wp + (size_t)t * 4) = a;
    *(u16x4v*)(Wp + PLANE + (size_t)t * 4) = s;
}

// Pack signs of two floats into one u32 of two bf16 (+1.0 / -1.0).
__device__ __forceinline__ unsigned int sgnpk(float hi, float lo) {
    return (__builtin_amdgcn_perm(__float_as_uint(hi), __float_as_uint(lo), 0x07000300u)
            & 0x80008000u) | 0x3F803F80u;
}

// ---------- main kernel ----------
__global__ __launch_bounds__(256, 3)
void lns_gemm_kernel(const float* __restrict__ X, const unsigned short* __restrict__ Wp,
                     const float* __restrict__ bias, float* __restrict__ out) {
    const int tid  = threadIdx.x;
    const int lane = tid & 63;
    const int wave = tid >> 6;
    const int quad = lane >> 4;
    const int l16  = lane & 15;
    const int nb   = blockIdx.x;                     // 0..3  (64-col N strip)
    const int mrow = blockIdx.y * 128 + wave * 32;   // wave-private 32-row M strip

    // A: frag mi -> row mrow + mi*16 + l16, k elems kb*32 + quad*8 .. +7 (fp32).
    // Wave covers 16 rows x 128 B contiguous per frag-load pair.
    const float* gA0 = X + (size_t)(mrow + l16) * K_DIM + quad * 8;
    const float* gA1 = gA0 + (size_t)16 * K_DIM;

    // B: frag ni -> row nb*64 + ni*16 + l16, k elems kb*32 + quad*8 (bf16, L2-hot).
    const unsigned short* gB = Wp + (size_t)(nb * 64 + l16) * K_DIM + quad * 8;

    f32x4 accP[2][4], accS[2][4];
#pragma unroll
    for (int i = 0; i < 2; ++i)
#pragma unroll
        for (int j = 0; j < 4; ++j) {
            accP[i][j] = (f32x4)(0.0f);
            accS[i][j] = (f32x4)(0.0f);
        }

    // A prefetch: 2 iters deep, ping-pong buffers (all indices compile-time).
    f32x4 ra0[4], ra1[4];  // each: [mi0 lo, mi0 hi, mi1 lo, mi1 hi]

#define LOAD_A(buf, kbv) do { \
        (buf)[0] = *(const f32x4*)(gA0 + (kbv) * 32); \
        (buf)[1] = *(const f32x4*)(gA0 + (kbv) * 32 + 4); \
        (buf)[2] = *(const f32x4*)(gA1 + (kbv) * 32); \
        (buf)[3] = *(const f32x4*)(gA1 + (kbv) * 32 + 4); \
    } while (0)

#define CONV_A(buf, aab, asg) do { \
        _Pragma("unroll") \
        for (int _mi = 0; _mi < 2; ++_mi) { \
            u16x8v _ab; \
            _Pragma("unroll") \
            for (int _j = 0; _j < 4; ++_j) { \
                _ab[_j]     = __builtin_bit_cast(unsigned short, (__bf16)__builtin_fabsf((buf)[2 * _mi][_j])); \
                _ab[_j + 4] = __builtin_bit_cast(unsigned short, (__bf16)__builtin_fabsf((buf)[2 * _mi + 1][_j])); \
            } \
            u32x4v _sg; \
            _sg[0] = sgnpk((buf)[2 * _mi][1],     (buf)[2 * _mi][0]); \
            _sg[1] = sgnpk((buf)[2 * _mi][3],     (buf)[2 * _mi][2]); \
            _sg[2] = sgnpk((buf)[2 * _mi + 1][1], (buf)[2 * _mi + 1][0]); \
            _sg[3] = sgnpk((buf)[2 * _mi + 1][3], (buf)[2 * _mi + 1][2]); \
            (aab)[_mi] = __builtin_bit_cast(bf16x8, _ab); \
            (asg)[_mi] = __builtin_bit_cast(bf16x8, _sg); \
        } \
    } while (0)

    // Prologue: A(0), A(1) in flight.
    LOAD_A(ra0, 0);
    LOAD_A(ra1, 1);

#pragma unroll
    for (int kb = 0; kb < 8; ++kb) {
        // 1) B(kb) loads first (L2-hot; oldest vmem this iter -> counted waits
        //    for B leave the younger A prefetch in flight).
        u16x8v bb_ab[4], bb_sg[4];
#pragma unroll
        for (int ni = 0; ni < 4; ++ni) {
            const unsigned short* bp = gB + (size_t)ni * 16 * K_DIM + kb * 32;
            bb_ab[ni] = *(const u16x8v*)bp;
            bb_sg[ni] = *(const u16x8v*)(bp + PLANE);
        }

        // 2) Convert A(kb) (landed: issued 2 iters ago) -> frags.
        bf16x8 aab[2], asg[2];
        if ((kb & 1) == 0) CONV_A(ra0, aab, asg);
        else               CONV_A(ra1, aab, asg);

        // 3) Refill the just-consumed buffer with A(kb+2).
        if (kb + 2 < 8) {
            if ((kb & 1) == 0) LOAD_A(ra0, kb + 2);
            else               LOAD_A(ra1, kb + 2);
        }

        // 4) MFMA.
#pragma unroll
        for (int ni = 0; ni < 4; ++ni) {
            bf16x8 bab = __builtin_bit_cast(bf16x8, bb_ab[ni]);
            bf16x8 bsg = __builtin_bit_cast(bf16x8, bb_sg[ni]);
            accP[0][ni] = __builtin_amdgcn_mfma_f32_16x16x32_bf16(aab[0], bab, accP[0][ni], 0, 0, 0);
            accP[1][ni] = __builtin_amdgcn_mfma_f32_16x16x32_bf16(aab[1], bab, accP[1][ni], 0, 0, 0);
            accS[0][ni] = __builtin_amdgcn_mfma_f32_16x16x32_bf16(asg[0], bsg, accS[0][ni], 0, 0, 0);
            accS[1][ni] = __builtin_amdgcn_mfma_f32_16x16x32_bf16(asg[1], bsg, accS[1][ni], 0, 0, 0);
        }
    }

    // ---- epilogue: C/D layout col = l16, row = quad*4 + reg ----
#pragma unroll
    for (int ni = 0; ni < 4; ++ni) {
        int n   = nb * 64 + ni * 16 + l16;
        float b = bias[n];
#pragma unroll
        for (int mi = 0; mi < 2; ++mi) {
            int mbase = mrow + mi * 16 + quad * 4;
#pragma unroll
            for (int r = 0; r < 4; ++r) {
                float p = accP[mi][ni][r];
                float s = accS[mi][ni][r];
                float v = (s > 0.0f) ? p : ((s < 0.0f) ? -p : 0.0f);
                out[(size_t)(mbase + r) * N_DIM + n] = v + b;
            }
        }
    }
}

extern "C" void kernel_launch(void* const* d_in, const int* in_sizes, int n_in,
                              void* d_out, int out_size, void* d_ws, size_t ws_size,
                              hipStream_t stream) {
    const float* x    = (const float*)d_in[0];
    const float* w    = (const float*)d_in[1];
    const float* bias = (const float*)d_in[2];
    float* out        = (float*)d_out;
    unsigned short* Wp = (unsigned short*)d_ws;  // 256 KB: abs plane + sgn plane (bf16)

    const int M = in_sizes[0] / K_DIM;  // 262144

    w_convert_kernel<<<dim3(64, 1, 1), dim3(256, 1, 1), 0, stream>>>(w, Wp);

    // nb fastest: 4 consecutive blocks share one 128-row X slab (L2/L3 reuse).
    dim3 grid(N_DIM / 64, M / 128, 1);  // (4, 2048)
    dim3 block(256, 1, 1);
    lns_gemm_kernel<<<grid, block, 0, stream>>>(x, Wp, bias, out);
}